// Round 3
// baseline (501.162 us; speedup 1.0000x reference)
//
#include <hip/hip_runtime.h>

// CapsuleConv2d: x (4,32,56,56) f32, weight (P_out=4,P_in=4,K=9,L_in=8,L_out=16) f32
// out (4,64,56,56) f32. 3x3 conv s1 p1, 3 routing iterations.
//
// Layout: lane = wl(8 consecutive w-sites, bits 0-2) x dh(d-half, bit 3) x p(bits 4-5).
// Each lane holds priors M[9][8] (its 8 d's) in registers; routing reductions over d
// are in-register FMAs + one xor-8 shuffle; final p-sum = xor-16/32 shuffles.
// Weight slice for this block's o (4x9x8x16 = 18 KB) staged in LDS, padded +4 floats
// per p-plane so the 8 distinct broadcast chunks are at worst 2-way bank aliased (free).

#define HW 56
#define HW2 3136

__global__ __launch_bounds__(256, 3) void caps_routing_kernel(
    const float* __restrict__ x, const float* __restrict__ wgt,
    float* __restrict__ out)
{
    __shared__ float lds_w[4 * 1156];   // per-p stride 1156 = 1152 + 4 pad

    const int tid = threadIdx.x;
    const int bx  = blockIdx.x;          // n*4 + o
    const int n = bx >> 2, o = bx & 3;

    // ---- stage weight slice wgt[o][p][k][l][d] (4608 floats) into LDS ----
    {
        const float4* wsrc = (const float4*)(wgt + o * 4608);
        for (int i = tid; i < 1152; i += 256) {
            const int pp  = i / 288;          // 288 float4 per p-plane
            const int rem = i - pp * 288;
            *(float4*)&lds_w[pp * 1156 + rem * 4] = wsrc[i];
        }
    }
    __syncthreads();

    const int wl = tid & 7;
    const int dh = (tid >> 3) & 1;
    const int p  = (tid >> 4) & 3;       // lane bits 4-5: input capsule plane
    // (R2 bug: tid>>4 unmasked gave p up to 15 -> OOB global + LDS reads -> GPU fault)

    const int t  = blockIdx.y * 4 + (tid >> 6);   // tile 0..391 (56 h x 7 w-tiles)
    const int h  = t / 7;
    const int w0 = (t - h * 7) * 8;

    // ---- priors: M[k][j] = sum_l x[n][p*8+l][h+kr-1][w0+wl+kc-1] * W[o][p][k][l][dh*8+j]
    float M[9][8];
    #pragma unroll
    for (int k = 0; k < 9; ++k)
        #pragma unroll
        for (int j = 0; j < 8; ++j) M[k][j] = 0.f;

    const float* xp = x + (n * 32 + p * 8) * HW2;
    const float* wbase = &lds_w[p * 1156 + dh * 8];
    const int colbase = w0 + wl - 1;

    for (int l = 0; l < 8; ++l) {
        #pragma unroll
        for (int rr = 0; rr < 3; ++rr) {
            const int row = h + rr - 1;
            const bool rv = (unsigned)row < (unsigned)HW;
            const float* xrow = xp + l * HW2 + row * HW;
            float xv[3];
            #pragma unroll
            for (int c = 0; c < 3; ++c) {
                const int col = colbase + c;
                xv[c] = (rv && (unsigned)col < (unsigned)HW) ? xrow[col] : 0.f;
            }
            #pragma unroll
            for (int kc = 0; kc < 3; ++kc) {
                const int k = rr * 3 + kc;
                const float4* wp = (const float4*)(wbase + (k * 8 + l) * 16);
                const float4 wa = wp[0];
                const float4 wb = wp[1];
                const float xs = xv[kc];
                M[k][0] += xs * wa.x; M[k][1] += xs * wa.y;
                M[k][2] += xs * wa.z; M[k][3] += xs * wa.w;
                M[k][4] += xs * wb.x; M[k][5] += xs * wb.y;
                M[k][6] += xs * wb.z; M[k][7] += xs * wb.w;
            }
        }
    }

    // ---- dynamic routing (3 iters; iter 0 has uniform probs = 1/9) ----
    float v[8], b[9];
    {
        float s[8];
        #pragma unroll
        for (int j = 0; j < 8; ++j) {
            float a = M[0][j];
            #pragma unroll
            for (int k = 1; k < 9; ++k) a += M[k][j];
            s[j] = a * (1.f / 9.f);
        }
        float sq = 0.f;
        #pragma unroll
        for (int j = 0; j < 8; ++j) sq += s[j] * s[j];
        sq += __shfl_xor(sq, 8, 64);
        const float scale = sq * __builtin_amdgcn_rsqf(sq) * __builtin_amdgcn_rcpf(1.f + sq);
        #pragma unroll
        for (int j = 0; j < 8; ++j) v[j] = s[j] * scale;
        #pragma unroll
        for (int k = 0; k < 9; ++k) {
            float u = 0.f;
            #pragma unroll
            for (int j = 0; j < 8; ++j) u += M[k][j] * v[j];
            u += __shfl_xor(u, 8, 64);
            b[k] = u;
        }
    }

    #pragma unroll
    for (int it = 1; it < 3; ++it) {
        float mx = b[0];
        #pragma unroll
        for (int k = 1; k < 9; ++k) mx = fmaxf(mx, b[k]);
        float e[9]; float se = 0.f;
        #pragma unroll
        for (int k = 0; k < 9; ++k) { e[k] = __expf(b[k] - mx); se += e[k]; }
        const float inv = __builtin_amdgcn_rcpf(se);
        float s[8];
        #pragma unroll
        for (int j = 0; j < 8; ++j) {
            float a = 0.f;
            #pragma unroll
            for (int k = 0; k < 9; ++k) a += e[k] * M[k][j];
            s[j] = a * inv;
        }
        float sq = 0.f;
        #pragma unroll
        for (int j = 0; j < 8; ++j) sq += s[j] * s[j];
        sq += __shfl_xor(sq, 8, 64);
        const float scale = sq * __builtin_amdgcn_rsqf(sq) * __builtin_amdgcn_rcpf(1.f + sq);
        #pragma unroll
        for (int j = 0; j < 8; ++j) v[j] = s[j] * scale;
        if (it == 1) {
            #pragma unroll
            for (int k = 0; k < 9; ++k) {
                float u = 0.f;
                #pragma unroll
                for (int j = 0; j < 8; ++j) u += M[k][j] * v[j];
                u += __shfl_xor(u, 8, 64);
                b[k] += u;
            }
        }
    }

    // ---- sum over p (lane bits 4,5), store ----
    #pragma unroll
    for (int j = 0; j < 8; ++j) {
        v[j] += __shfl_xor(v[j], 16, 64);
        v[j] += __shfl_xor(v[j], 32, 64);
    }
    if (p == 0) {
        float* op = out + ((n * 64 + o * 16 + dh * 8) * HW + h) * HW + w0 + wl;
        #pragma unroll
        for (int j = 0; j < 8; ++j) op[j * HW2] = v[j];
    }
}

extern "C" void kernel_launch(void* const* d_in, const int* in_sizes, int n_in,
                              void* d_out, int out_size, void* d_ws, size_t ws_size,
                              hipStream_t stream) {
    const float* x   = (const float*)d_in[0];
    const float* wgt = (const float*)d_in[1];
    float* out = (float*)d_out;

    // grid: x = n*4+o (16), y = 98 blocks of 4 wave-tiles -> 392 tiles = 56 h x 7 wtiles
    caps_routing_kernel<<<dim3(16, 98), dim3(256), 0, stream>>>(x, wgt, out);
}

// Round 4
// 397.332 us; speedup vs baseline: 1.2613x; 1.2613x over previous
//
#include <hip/hip_runtime.h>

// CapsuleConv2d: x (4,32,56,56) f32, weight (P_out=4,P_in=4,K=9,L_in=8,L_out=16) f32
// out (4,64,56,56) f32. 3x3 conv s1 p1, 3 routing iterations.
//
// Lane = wl(bits 0-1: 4 w-sites) x dq(bits 2-3: d-quarter) x p(bits 4-5: input plane).
// Each lane holds M[9][4] (its 4 d's) -> ~77 VGPR footprint, fits even if the
// allocator targets 6 waves/EU (84 regs) -- R3's M[9][8] spilled to scratch there
// (887 MB scratch writes, 462 us). d-reductions = in-register + xor4/xor8 shuffles;
// p-sum = xor16/xor32. Weight slice (18 KB) in LDS with per-p stride 1168
// (== 16 mod 32) so the 16 distinct (dq,p) b128 broadcast reads start at banks
// 0,4,...,60 -> exact 2-way coverage (free per m136).

#define HW 56
#define HW2 3136
#define WSTRIDE 1168

__global__ __launch_bounds__(256, 4) void caps_routing_kernel(
    const float* __restrict__ x, const float* __restrict__ wgt,
    float* __restrict__ out)
{
    __shared__ float lds_w[4 * WSTRIDE];   // 18688 B

    const int tid = threadIdx.x;
    const int bx  = blockIdx.x;          // n*4 + o
    const int n = bx >> 2, o = bx & 3;

    // ---- stage weight slice wgt[o][p][k][l][d] (4608 floats) into LDS ----
    {
        const float4* wsrc = (const float4*)(wgt + o * 4608);
        for (int i = tid; i < 1152; i += 256) {
            const int pp  = i / 288;          // 288 float4 per p-plane
            const int rem = i - pp * 288;
            *(float4*)&lds_w[pp * WSTRIDE + rem * 4] = wsrc[i];
        }
    }
    __syncthreads();

    const int wl = tid & 3;
    const int dq = (tid >> 2) & 3;
    const int p  = (tid >> 4) & 3;

    const int t  = blockIdx.y * 4 + (tid >> 6);   // tile 0..783 (56 h x 14 w-tiles)
    const int h  = t / 14;
    const int w0 = (t - h * 14) * 4;

    // ---- priors: M[k][j] = sum_l x[n][p*8+l][h+rr-1][w0+wl+kc-1] * W[o][p][k][l][dq*4+j]
    float M[9][4];
    #pragma unroll
    for (int k = 0; k < 9; ++k)
        #pragma unroll
        for (int j = 0; j < 4; ++j) M[k][j] = 0.f;

    const float* xp = x + (n * 32 + p * 8) * HW2;
    const float* wbase = &lds_w[p * WSTRIDE + dq * 4];
    const int colbase = w0 + wl - 1;

    for (int l = 0; l < 8; ++l) {
        #pragma unroll
        for (int rr = 0; rr < 3; ++rr) {
            const int row = h + rr - 1;
            const bool rv = (unsigned)row < (unsigned)HW;
            const float* xrow = xp + l * HW2 + row * HW;
            float xv[3];
            #pragma unroll
            for (int c = 0; c < 3; ++c) {
                const int col = colbase + c;
                xv[c] = (rv && (unsigned)col < (unsigned)HW) ? xrow[col] : 0.f;
            }
            #pragma unroll
            for (int kc = 0; kc < 3; ++kc) {
                const int k = rr * 3 + kc;
                const float4 wa = *(const float4*)(wbase + (k * 8 + l) * 16);
                const float xs = xv[kc];
                M[k][0] += xs * wa.x; M[k][1] += xs * wa.y;
                M[k][2] += xs * wa.z; M[k][3] += xs * wa.w;
            }
        }
    }

    // ---- dynamic routing (3 iters; iter 0 has uniform probs = 1/9) ----
    float v[4], b[9];
    {
        float s[4];
        #pragma unroll
        for (int j = 0; j < 4; ++j) {
            float a = M[0][j];
            #pragma unroll
            for (int k = 1; k < 9; ++k) a += M[k][j];
            s[j] = a * (1.f / 9.f);
        }
        float sq = s[0]*s[0] + s[1]*s[1] + s[2]*s[2] + s[3]*s[3];
        sq += __shfl_xor(sq, 4, 64);
        sq += __shfl_xor(sq, 8, 64);
        const float scale = sq * __builtin_amdgcn_rsqf(sq) * __builtin_amdgcn_rcpf(1.f + sq);
        #pragma unroll
        for (int j = 0; j < 4; ++j) v[j] = s[j] * scale;
        #pragma unroll
        for (int k = 0; k < 9; ++k) {
            float u = M[k][0]*v[0] + M[k][1]*v[1] + M[k][2]*v[2] + M[k][3]*v[3];
            u += __shfl_xor(u, 4, 64);
            u += __shfl_xor(u, 8, 64);
            b[k] = u;
        }
    }

    #pragma unroll
    for (int it = 1; it < 3; ++it) {
        float mx = b[0];
        #pragma unroll
        for (int k = 1; k < 9; ++k) mx = fmaxf(mx, b[k]);
        float e[9]; float se = 0.f;
        #pragma unroll
        for (int k = 0; k < 9; ++k) { e[k] = __expf(b[k] - mx); se += e[k]; }
        const float inv = __builtin_amdgcn_rcpf(se);
        float s[4];
        #pragma unroll
        for (int j = 0; j < 4; ++j) {
            float a = 0.f;
            #pragma unroll
            for (int k = 0; k < 9; ++k) a += e[k] * M[k][j];
            s[j] = a * inv;
        }
        float sq = s[0]*s[0] + s[1]*s[1] + s[2]*s[2] + s[3]*s[3];
        sq += __shfl_xor(sq, 4, 64);
        sq += __shfl_xor(sq, 8, 64);
        const float scale = sq * __builtin_amdgcn_rsqf(sq) * __builtin_amdgcn_rcpf(1.f + sq);
        #pragma unroll
        for (int j = 0; j < 4; ++j) v[j] = s[j] * scale;
        if (it == 1) {
            #pragma unroll
            for (int k = 0; k < 9; ++k) {
                float u = M[k][0]*v[0] + M[k][1]*v[1] + M[k][2]*v[2] + M[k][3]*v[3];
                u += __shfl_xor(u, 4, 64);
                u += __shfl_xor(u, 8, 64);
                b[k] += u;
            }
        }
    }

    // ---- sum over p (lane bits 4,5), store ----
    #pragma unroll
    for (int j = 0; j < 4; ++j) {
        v[j] += __shfl_xor(v[j], 16, 64);
        v[j] += __shfl_xor(v[j], 32, 64);
    }
    if (p == 0) {
        float* op = out + ((n * 64 + o * 16 + dq * 4) * HW + h) * HW + w0 + wl;
        #pragma unroll
        for (int j = 0; j < 4; ++j) op[j * HW2] = v[j];
    }
}

extern "C" void kernel_launch(void* const* d_in, const int* in_sizes, int n_in,
                              void* d_out, int out_size, void* d_ws, size_t ws_size,
                              hipStream_t stream) {
    const float* x   = (const float*)d_in[0];
    const float* wgt = (const float*)d_in[1];
    float* out = (float*)d_out;

    // grid: x = n*4+o (16), y = 196 blocks of 4 wave-tiles -> 784 tiles = 56 h x 14 wtiles
    caps_routing_kernel<<<dim3(16, 196), dim3(256), 0, stream>>>(x, wgt, out);
}

// Round 5
// 220.926 us; speedup vs baseline: 2.2685x; 1.7985x over previous
//
#include <hip/hip_runtime.h>

// CapsuleConv2d: x (4,32,56,56) f32, weight (P_out=4,P_in=4,K=9,L_in=8,L_out=16) f32
// out (4,64,56,56) f32. 3x3 conv s1 p1, 3 routing iterations.
//
// Lane = wl(bits 0-1: 4 w-sites) x dq(bits 2-3: d-quarter) x p(bits 4-5: input plane).
// Each lane holds M[9][4] in registers. d-reductions = in-register + xor4/xor8
// shuffles; p-sum = xor16/xor32. Weight slice (18 KB) in LDS, per-p stride 1168.
//
// REGISTER LESSON (R3/R4): __launch_bounds__(256,N) acted as a HARD min-occupancy
// of 2N waves/EU -> allocator spilled M to scratch to meet it (VGPR forced to
// 512/6=84, then 512/8=64; 783 MB scratch traffic, 327-462 us). Use
// amdgpu_waves_per_eu(2) instead: min 2 waves/EU = up to 256 VGPRs before any
// spill; natural pressure ~90 regs -> no spill.

#define HW 56
#define HW2 3136
#define WSTRIDE 1168

__global__ __launch_bounds__(256)
__attribute__((amdgpu_waves_per_eu(2)))
void caps_routing_kernel(
    const float* __restrict__ x, const float* __restrict__ wgt,
    float* __restrict__ out)
{
    __shared__ float lds_w[4 * WSTRIDE];   // 18688 B

    const int tid = threadIdx.x;
    const int bx  = blockIdx.x;          // n*4 + o
    const int n = bx >> 2, o = bx & 3;

    // ---- stage weight slice wgt[o][p][k][l][d] (4608 floats) into LDS ----
    {
        const float4* wsrc = (const float4*)(wgt + o * 4608);
        for (int i = tid; i < 1152; i += 256) {
            const int pp  = i / 288;          // 288 float4 per p-plane
            const int rem = i - pp * 288;
            *(float4*)&lds_w[pp * WSTRIDE + rem * 4] = wsrc[i];
        }
    }
    __syncthreads();

    const int wl = tid & 3;
    const int dq = (tid >> 2) & 3;
    const int p  = (tid >> 4) & 3;

    const int t  = blockIdx.y * 4 + (tid >> 6);   // tile 0..783 (56 h x 14 w-tiles)
    const int h  = t / 14;
    const int w0 = (t - h * 14) * 4;

    // ---- priors: M[k][j] = sum_l x[n][p*8+l][h+rr-1][w0+wl+kc-1] * W[o][p][k][l][dq*4+j]
    float M[9][4];
    #pragma unroll
    for (int k = 0; k < 9; ++k)
        #pragma unroll
        for (int j = 0; j < 4; ++j) M[k][j] = 0.f;

    const float* xp = x + (n * 32 + p * 8) * HW2;
    const float* wbase = &lds_w[p * WSTRIDE + dq * 4];
    const int colbase = w0 + wl - 1;

    for (int l = 0; l < 8; ++l) {
        #pragma unroll
        for (int rr = 0; rr < 3; ++rr) {
            const int row = h + rr - 1;
            const bool rv = (unsigned)row < (unsigned)HW;
            const float* xrow = xp + l * HW2 + row * HW;
            float xv[3];
            #pragma unroll
            for (int c = 0; c < 3; ++c) {
                const int col = colbase + c;
                xv[c] = (rv && (unsigned)col < (unsigned)HW) ? xrow[col] : 0.f;
            }
            #pragma unroll
            for (int kc = 0; kc < 3; ++kc) {
                const int k = rr * 3 + kc;
                const float4 wa = *(const float4*)(wbase + (k * 8 + l) * 16);
                const float xs = xv[kc];
                M[k][0] += xs * wa.x; M[k][1] += xs * wa.y;
                M[k][2] += xs * wa.z; M[k][3] += xs * wa.w;
            }
        }
    }

    // ---- dynamic routing (3 iters; iter 0 has uniform probs = 1/9) ----
    float v[4], b[9];
    {
        float s[4];
        #pragma unroll
        for (int j = 0; j < 4; ++j) {
            float a = M[0][j];
            #pragma unroll
            for (int k = 1; k < 9; ++k) a += M[k][j];
            s[j] = a * (1.f / 9.f);
        }
        float sq = s[0]*s[0] + s[1]*s[1] + s[2]*s[2] + s[3]*s[3];
        sq += __shfl_xor(sq, 4, 64);
        sq += __shfl_xor(sq, 8, 64);
        const float scale = sq * __builtin_amdgcn_rsqf(sq) * __builtin_amdgcn_rcpf(1.f + sq);
        #pragma unroll
        for (int j = 0; j < 4; ++j) v[j] = s[j] * scale;
        #pragma unroll
        for (int k = 0; k < 9; ++k) {
            float u = M[k][0]*v[0] + M[k][1]*v[1] + M[k][2]*v[2] + M[k][3]*v[3];
            u += __shfl_xor(u, 4, 64);
            u += __shfl_xor(u, 8, 64);
            b[k] = u;
        }
    }

    #pragma unroll
    for (int it = 1; it < 3; ++it) {
        float mx = b[0];
        #pragma unroll
        for (int k = 1; k < 9; ++k) mx = fmaxf(mx, b[k]);
        float e[9]; float se = 0.f;
        #pragma unroll
        for (int k = 0; k < 9; ++k) { e[k] = __expf(b[k] - mx); se += e[k]; }
        const float inv = __builtin_amdgcn_rcpf(se);
        float s[4];
        #pragma unroll
        for (int j = 0; j < 4; ++j) {
            float a = 0.f;
            #pragma unroll
            for (int k = 0; k < 9; ++k) a += e[k] * M[k][j];
            s[j] = a * inv;
        }
        float sq = s[0]*s[0] + s[1]*s[1] + s[2]*s[2] + s[3]*s[3];
        sq += __shfl_xor(sq, 4, 64);
        sq += __shfl_xor(sq, 8, 64);
        const float scale = sq * __builtin_amdgcn_rsqf(sq) * __builtin_amdgcn_rcpf(1.f + sq);
        #pragma unroll
        for (int j = 0; j < 4; ++j) v[j] = s[j] * scale;
        if (it == 1) {
            #pragma unroll
            for (int k = 0; k < 9; ++k) {
                float u = M[k][0]*v[0] + M[k][1]*v[1] + M[k][2]*v[2] + M[k][3]*v[3];
                u += __shfl_xor(u, 4, 64);
                u += __shfl_xor(u, 8, 64);
                b[k] += u;
            }
        }
    }

    // ---- sum over p (lane bits 4,5), store ----
    #pragma unroll
    for (int j = 0; j < 4; ++j) {
        v[j] += __shfl_xor(v[j], 16, 64);
        v[j] += __shfl_xor(v[j], 32, 64);
    }
    if (p == 0) {
        float* op = out + ((n * 64 + o * 16 + dq * 4) * HW + h) * HW + w0 + wl;
        #pragma unroll
        for (int j = 0; j < 4; ++j) op[j * HW2] = v[j];
    }
}

extern "C" void kernel_launch(void* const* d_in, const int* in_sizes, int n_in,
                              void* d_out, int out_size, void* d_ws, size_t ws_size,
                              hipStream_t stream) {
    const float* x   = (const float*)d_in[0];
    const float* wgt = (const float*)d_in[1];
    float* out = (float*)d_out;

    // grid: x = n*4+o (16), y = 196 blocks of 4 wave-tiles -> 784 tiles = 56 h x 14 wtiles
    caps_routing_kernel<<<dim3(16, 196), dim3(256), 0, stream>>>(x, wgt, out);
}

// Round 6
// 82.082 us; speedup vs baseline: 6.1056x; 2.6915x over previous
//
#include <hip/hip_runtime.h>

// CapsuleConv2d: x (4,32,56,56) f32, weight (P_out=4,P_in=4,K=9,L_in=8,L_out=16) f32
// out (4,64,56,56) f32. 3x3 conv s1 p1, 3 routing iterations.
//
// Lane = wl(bits 0-1: 4 w-sites) x dq(bits 2-3: d-quarter) x p(bits 4-5: input plane).
// Each lane holds M[9][4] in registers. d-reductions = in-register + xor4/xor8
// shuffles; p-sum = xor16/xor32. Weight slice (18 KB) in LDS, per-p stride 1168.
//
// REGISTER LESSONS:
//  R3/R4: __launch_bounds__(256,N) = hard min-occupancy -> forced VGPR to 84/64,
//         M spilled, 780/370 MB scratch traffic.
//  R5: amdgpu_waves_per_eu(2) still capped at 128 VGPR and the FULLY-UNROLLED
//      l-loop let the scheduler cluster 72 global + 72 LDS loads -> live set
//      >128 -> still spilling (370 MB writes).
//  Fix: NO occupancy attributes at all (m97 proves default allows >128 VGPR),
//      and unroll(disable) on the l-loop so pressure stays ~70 regs.

#define HW 56
#define HW2 3136
#define WSTRIDE 1168

__global__ void caps_routing_kernel(
    const float* __restrict__ x, const float* __restrict__ wgt,
    float* __restrict__ out)
{
    __shared__ float lds_w[4 * WSTRIDE];   // 18688 B

    const int tid = threadIdx.x;
    const int bx  = blockIdx.x;          // n*4 + o
    const int n = bx >> 2, o = bx & 3;

    // ---- stage weight slice wgt[o][p][k][l][d] (4608 floats) into LDS ----
    {
        const float4* wsrc = (const float4*)(wgt + o * 4608);
        for (int i = tid; i < 1152; i += 256) {
            const int pp  = i / 288;          // 288 float4 per p-plane
            const int rem = i - pp * 288;
            *(float4*)&lds_w[pp * WSTRIDE + rem * 4] = wsrc[i];
        }
    }
    __syncthreads();

    const int wl = tid & 3;
    const int dq = (tid >> 2) & 3;
    const int p  = (tid >> 4) & 3;

    const int t  = blockIdx.y * 4 + (tid >> 6);   // tile 0..783 (56 h x 14 w-tiles)
    const int h  = t / 14;
    const int w0 = (t - h * 14) * 4;

    // ---- priors: M[k][j] = sum_l x[n][p*8+l][h+rr-1][w0+wl+kc-1] * W[o][p][k][l][dq*4+j]
    float M[9][4];
    #pragma unroll
    for (int k = 0; k < 9; ++k)
        #pragma unroll
        for (int j = 0; j < 4; ++j) M[k][j] = 0.f;

    const float* xp = x + (n * 32 + p * 8) * HW2;
    const float* wbase = &lds_w[p * WSTRIDE + dq * 4];
    const int colbase = w0 + wl - 1;

    #pragma clang loop unroll(disable)
    for (int l = 0; l < 8; ++l) {
        #pragma unroll
        for (int rr = 0; rr < 3; ++rr) {
            const int row = h + rr - 1;
            const bool rv = (unsigned)row < (unsigned)HW;
            const float* xrow = xp + l * HW2 + row * HW;
            float xv[3];
            #pragma unroll
            for (int c = 0; c < 3; ++c) {
                const int col = colbase + c;
                xv[c] = (rv && (unsigned)col < (unsigned)HW) ? xrow[col] : 0.f;
            }
            #pragma unroll
            for (int kc = 0; kc < 3; ++kc) {
                const int k = rr * 3 + kc;
                const float4 wa = *(const float4*)(wbase + (k * 8 + l) * 16);
                const float xs = xv[kc];
                M[k][0] += xs * wa.x; M[k][1] += xs * wa.y;
                M[k][2] += xs * wa.z; M[k][3] += xs * wa.w;
            }
        }
    }

    // ---- dynamic routing (3 iters; iter 0 has uniform probs = 1/9) ----
    float v[4], b[9];
    {
        float s[4];
        #pragma unroll
        for (int j = 0; j < 4; ++j) {
            float a = M[0][j];
            #pragma unroll
            for (int k = 1; k < 9; ++k) a += M[k][j];
            s[j] = a * (1.f / 9.f);
        }
        float sq = s[0]*s[0] + s[1]*s[1] + s[2]*s[2] + s[3]*s[3];
        sq += __shfl_xor(sq, 4, 64);
        sq += __shfl_xor(sq, 8, 64);
        const float scale = sq * __builtin_amdgcn_rsqf(sq) * __builtin_amdgcn_rcpf(1.f + sq);
        #pragma unroll
        for (int j = 0; j < 4; ++j) v[j] = s[j] * scale;
        #pragma unroll
        for (int k = 0; k < 9; ++k) {
            float u = M[k][0]*v[0] + M[k][1]*v[1] + M[k][2]*v[2] + M[k][3]*v[3];
            u += __shfl_xor(u, 4, 64);
            u += __shfl_xor(u, 8, 64);
            b[k] = u;
        }
    }

    #pragma unroll
    for (int it = 1; it < 3; ++it) {
        float mx = b[0];
        #pragma unroll
        for (int k = 1; k < 9; ++k) mx = fmaxf(mx, b[k]);
        float e[9]; float se = 0.f;
        #pragma unroll
        for (int k = 0; k < 9; ++k) { e[k] = __expf(b[k] - mx); se += e[k]; }
        const float inv = __builtin_amdgcn_rcpf(se);
        float s[4];
        #pragma unroll
        for (int j = 0; j < 4; ++j) {
            float a = 0.f;
            #pragma unroll
            for (int k = 0; k < 9; ++k) a += e[k] * M[k][j];
            s[j] = a * inv;
        }
        float sq = s[0]*s[0] + s[1]*s[1] + s[2]*s[2] + s[3]*s[3];
        sq += __shfl_xor(sq, 4, 64);
        sq += __shfl_xor(sq, 8, 64);
        const float scale = sq * __builtin_amdgcn_rsqf(sq) * __builtin_amdgcn_rcpf(1.f + sq);
        #pragma unroll
        for (int j = 0; j < 4; ++j) v[j] = s[j] * scale;
        if (it == 1) {
            #pragma unroll
            for (int k = 0; k < 9; ++k) {
                float u = M[k][0]*v[0] + M[k][1]*v[1] + M[k][2]*v[2] + M[k][3]*v[3];
                u += __shfl_xor(u, 4, 64);
                u += __shfl_xor(u, 8, 64);
                b[k] += u;
            }
        }
    }

    // ---- sum over p (lane bits 4,5), store ----
    #pragma unroll
    for (int j = 0; j < 4; ++j) {
        v[j] += __shfl_xor(v[j], 16, 64);
        v[j] += __shfl_xor(v[j], 32, 64);
    }
    if (p == 0) {
        float* op = out + ((n * 64 + o * 16 + dq * 4) * HW + h) * HW + w0 + wl;
        #pragma unroll
        for (int j = 0; j < 4; ++j) op[j * HW2] = v[j];
    }
}

extern "C" void kernel_launch(void* const* d_in, const int* in_sizes, int n_in,
                              void* d_out, int out_size, void* d_ws, size_t ws_size,
                              hipStream_t stream) {
    const float* x   = (const float*)d_in[0];
    const float* wgt = (const float*)d_in[1];
    float* out = (float*)d_out;

    // grid: x = n*4+o (16), y = 196 blocks of 4 wave-tiles -> 784 tiles = 56 h x 14 wtiles
    caps_routing_kernel<<<dim3(16, 196), dim3(256), 0, stream>>>(x, wgt, out);
}

// Round 7
// 77.940 us; speedup vs baseline: 6.4301x; 1.0531x over previous
//
#include <hip/hip_runtime.h>

// CapsuleConv2d: x (4,32,56,56) f32, weight (P_out=4,P_in=4,K=9,L_in=8,L_out=16) f32
// out (4,64,56,56) f32. 3x3 conv s1 p1, 3 routing iterations.
//
// Lane = wl(bits 0-1: 4 w-sites) x dq(bits 2-3: d-quarter) x p(bits 4-5: input plane).
// T=2: each wave owns two h-ADJACENT tiles (h0, h0+1) -> one ds_read_b128 weight
// broadcast feeds 8 sites (R6: 4), halving the dominant DS-pipe cost (~17.6 us ->
// ~8.8 us model); the two tiles' conv windows share rows h0..h0+1 so x-loads are
// 12/l-iter (4 rows x 3 cols) instead of 2x9. M[9][4][2] = 72 VGPRs.
//
// REGISTER LESSONS (R3-R6): any occupancy attribute caused forced spills
// (84/64/128-cap -> up to 887 MB scratch). NO attributes + unroll(disable) on the
// l-loop keeps live set ~120 and eliminated all scratch traffic (R6).

#define HW 56
#define HW2 3136
#define WSTRIDE 1168

__global__ void caps_routing_kernel(
    const float* __restrict__ x, const float* __restrict__ wgt,
    float* __restrict__ out)
{
    __shared__ float lds_w[4 * WSTRIDE];   // 18688 B

    const int tid = threadIdx.x;
    const int bx  = blockIdx.x;          // n*4 + o
    const int n = bx >> 2, o = bx & 3;

    // ---- stage weight slice wgt[o][p][k][l][d] (4608 floats) into LDS ----
    {
        const float4* wsrc = (const float4*)(wgt + o * 4608);
        for (int i = tid; i < 1152; i += 256) {
            const int pp  = i / 288;          // 288 float4 per p-plane
            const int rem = i - pp * 288;
            *(float4*)&lds_w[pp * WSTRIDE + rem * 4] = wsrc[i];
        }
    }
    __syncthreads();

    const int wl = tid & 3;
    const int dq = (tid >> 2) & 3;
    const int p  = (tid >> 4) & 3;

    // tile-pair index: 392 pairs = 28 h-pairs x 14 w-tiles
    const int t  = blockIdx.y * 4 + (tid >> 6);
    const int hp = t / 14;
    const int w0 = (t - hp * 14) * 4;
    const int h0 = hp * 2;               // wave covers rows h0 and h0+1

    // M[k][j][ti]: priors for the lane's 4 d's at sites (h0+ti, w0+wl)
    float M[9][4][2];
    #pragma unroll
    for (int k = 0; k < 9; ++k)
        #pragma unroll
        for (int j = 0; j < 4; ++j) { M[k][j][0] = 0.f; M[k][j][1] = 0.f; }

    const float* xp = x + (n * 32 + p * 8) * HW2;
    const float* wbase = &lds_w[p * WSTRIDE + dq * 4];
    const int colbase = w0 + wl - 1;

    #pragma clang loop unroll(disable)
    for (int l = 0; l < 8; ++l) {
        // 4 rows (h0-1 .. h0+2) x 3 cols, shared between the two tiles
        float xv[4][3];
        const float* xplane = xp + l * HW2;
        #pragma unroll
        for (int rr = 0; rr < 4; ++rr) {
            const int row = h0 + rr - 1;
            const bool rv = (unsigned)row < (unsigned)HW;
            const float* xrow = xplane + row * HW;
            #pragma unroll
            for (int c = 0; c < 3; ++c) {
                const int col = colbase + c;
                xv[rr][c] = (rv && (unsigned)col < (unsigned)HW) ? xrow[col] : 0.f;
            }
        }
        #pragma unroll
        for (int rr = 0; rr < 3; ++rr) {
            #pragma unroll
            for (int kc = 0; kc < 3; ++kc) {
                const int k = rr * 3 + kc;
                const float4 wa = *(const float4*)(wbase + (k * 8 + l) * 16);
                const float xs0 = xv[rr][kc];       // tile 0 (row h0)
                const float xs1 = xv[rr + 1][kc];   // tile 1 (row h0+1)
                M[k][0][0] += xs0 * wa.x; M[k][1][0] += xs0 * wa.y;
                M[k][2][0] += xs0 * wa.z; M[k][3][0] += xs0 * wa.w;
                M[k][0][1] += xs1 * wa.x; M[k][1][1] += xs1 * wa.y;
                M[k][2][1] += xs1 * wa.z; M[k][3][1] += xs1 * wa.w;
            }
        }
    }

    // ---- dynamic routing (3 iters; iter 0 uniform probs = 1/9), per tile ----
    #pragma unroll
    for (int ti = 0; ti < 2; ++ti) {
        float v[4], b[9];
        {
            float s[4];
            #pragma unroll
            for (int j = 0; j < 4; ++j) {
                float a = M[0][j][ti];
                #pragma unroll
                for (int k = 1; k < 9; ++k) a += M[k][j][ti];
                s[j] = a * (1.f / 9.f);
            }
            float sq = s[0]*s[0] + s[1]*s[1] + s[2]*s[2] + s[3]*s[3];
            sq += __shfl_xor(sq, 4, 64);
            sq += __shfl_xor(sq, 8, 64);
            const float scale = sq * __builtin_amdgcn_rsqf(sq) * __builtin_amdgcn_rcpf(1.f + sq);
            #pragma unroll
            for (int j = 0; j < 4; ++j) v[j] = s[j] * scale;
            #pragma unroll
            for (int k = 0; k < 9; ++k) {
                float u = M[k][0][ti]*v[0] + M[k][1][ti]*v[1]
                        + M[k][2][ti]*v[2] + M[k][3][ti]*v[3];
                u += __shfl_xor(u, 4, 64);
                u += __shfl_xor(u, 8, 64);
                b[k] = u;
            }
        }

        #pragma unroll
        for (int it = 1; it < 3; ++it) {
            float mx = b[0];
            #pragma unroll
            for (int k = 1; k < 9; ++k) mx = fmaxf(mx, b[k]);
            float e[9]; float se = 0.f;
            #pragma unroll
            for (int k = 0; k < 9; ++k) { e[k] = __expf(b[k] - mx); se += e[k]; }
            const float inv = __builtin_amdgcn_rcpf(se);
            float s[4];
            #pragma unroll
            for (int j = 0; j < 4; ++j) {
                float a = 0.f;
                #pragma unroll
                for (int k = 0; k < 9; ++k) a += e[k] * M[k][j][ti];
                s[j] = a * inv;
            }
            float sq = s[0]*s[0] + s[1]*s[1] + s[2]*s[2] + s[3]*s[3];
            sq += __shfl_xor(sq, 4, 64);
            sq += __shfl_xor(sq, 8, 64);
            const float scale = sq * __builtin_amdgcn_rsqf(sq) * __builtin_amdgcn_rcpf(1.f + sq);
            #pragma unroll
            for (int j = 0; j < 4; ++j) v[j] = s[j] * scale;
            if (it == 1) {
                #pragma unroll
                for (int k = 0; k < 9; ++k) {
                    float u = M[k][0][ti]*v[0] + M[k][1][ti]*v[1]
                            + M[k][2][ti]*v[2] + M[k][3][ti]*v[3];
                    u += __shfl_xor(u, 4, 64);
                    u += __shfl_xor(u, 8, 64);
                    b[k] += u;
                }
            }
        }

        // ---- sum over p (lane bits 4,5), store row h0+ti ----
        #pragma unroll
        for (int j = 0; j < 4; ++j) {
            v[j] += __shfl_xor(v[j], 16, 64);
            v[j] += __shfl_xor(v[j], 32, 64);
        }
        if (p == 0) {
            float* op = out + ((n * 64 + o * 16 + dq * 4) * HW + (h0 + ti)) * HW + w0 + wl;
            #pragma unroll
            for (int j = 0; j < 4; ++j) op[j * HW2] = v[j];
        }
    }
}

extern "C" void kernel_launch(void* const* d_in, const int* in_sizes, int n_in,
                              void* d_out, int out_size, void* d_ws, size_t ws_size,
                              hipStream_t stream) {
    const float* x   = (const float*)d_in[0];
    const float* wgt = (const float*)d_in[1];
    float* out = (float*)d_out;

    // grid: x = n*4+o (16), y = 98 blocks of 4 wave tile-pairs
    //       392 pairs = 28 h-pairs x 14 w-tiles
    caps_routing_kernel<<<dim3(16, 98), dim3(256), 0, stream>>>(x, wgt, out);
}

// Round 8
// 77.735 us; speedup vs baseline: 6.4471x; 1.0026x over previous
//
#include <hip/hip_runtime.h>

// CapsuleConv2d: x (4,32,56,56) f32, weight (P_out=4,P_in=4,K=9,L_in=8,L_out=16) f32
// out (4,64,56,56) f32. 3x3 conv s1 p1, 3 routing iterations.
//
// Lane = dq(bits 0-1: d-quarter) x wl(bits 2-3: 4 w-sites) x p(bits 4-5: plane).
// dq in the QUAD bits so the d-reduction (squash norm, logit updates) is two DPP
// quad_perm adds (pure VALU, no DS pipe) instead of xor4/xor8 ds_swizzles -- R7's
// routing burned ~6 us of DS on those. T=2: each wave owns two h-adjacent tiles;
// one ds_read_b128 weight broadcast feeds 8 sites. M[9][4][2] = 72 VGPRs.
//
// REGISTER LESSONS (R3-R6): any occupancy attribute caused forced spills
// (84/64/128-cap -> up to 887 MB scratch). NO attributes + unroll(disable) on the
// l-loop keeps live set ~120 and eliminated all scratch traffic (R6).

#define HW 56
#define HW2 3136
#define WSTRIDE 1168

// sum over the 4 lanes of a quad: x + quad_perm[1,0,3,2] then + quad_perm[2,3,0,1]
__device__ __forceinline__ float quad_add1(float x) {
    int y = __builtin_amdgcn_update_dpp(0, __float_as_int(x), 0xB1, 0xF, 0xF, true);
    return x + __int_as_float(y);
}
__device__ __forceinline__ float quad_add2(float x) {
    int y = __builtin_amdgcn_update_dpp(0, __float_as_int(x), 0x4E, 0xF, 0xF, true);
    return x + __int_as_float(y);
}
__device__ __forceinline__ float quad_reduce(float x) {
    return quad_add2(quad_add1(x));
}

__global__ void caps_routing_kernel(
    const float* __restrict__ x, const float* __restrict__ wgt,
    float* __restrict__ out)
{
    __shared__ float lds_w[4 * WSTRIDE];   // 18688 B

    const int tid = threadIdx.x;
    const int bx  = blockIdx.x;          // n*4 + o
    const int n = bx >> 2, o = bx & 3;

    // ---- stage weight slice wgt[o][p][k][l][d] (4608 floats) into LDS ----
    {
        const float4* wsrc = (const float4*)(wgt + o * 4608);
        for (int i = tid; i < 1152; i += 256) {
            const int pp  = i / 288;          // 288 float4 per p-plane
            const int rem = i - pp * 288;
            *(float4*)&lds_w[pp * WSTRIDE + rem * 4] = wsrc[i];
        }
    }
    __syncthreads();

    const int dq = tid & 3;              // quad bits -> DPP-reducible
    const int wl = (tid >> 2) & 3;
    const int p  = (tid >> 4) & 3;

    // tile-pair index: 392 pairs = 28 h-pairs x 14 w-tiles
    const int t  = blockIdx.y * 4 + (tid >> 6);
    const int hp = t / 14;
    const int w0 = (t - hp * 14) * 4;
    const int h0 = hp * 2;               // wave covers rows h0 and h0+1

    // M[k][j][ti]: priors for the lane's 4 d's at sites (h0+ti, w0+wl)
    float M[9][4][2];
    #pragma unroll
    for (int k = 0; k < 9; ++k)
        #pragma unroll
        for (int j = 0; j < 4; ++j) { M[k][j][0] = 0.f; M[k][j][1] = 0.f; }

    const float* xp = x + (n * 32 + p * 8) * HW2;
    const float* wbase = &lds_w[p * WSTRIDE + dq * 4];
    const int colbase = w0 + wl - 1;

    #pragma clang loop unroll(disable)
    for (int l = 0; l < 8; ++l) {
        // 4 rows (h0-1 .. h0+2) x 3 cols, shared between the two tiles
        float xv[4][3];
        const float* xplane = xp + l * HW2;
        #pragma unroll
        for (int rr = 0; rr < 4; ++rr) {
            const int row = h0 + rr - 1;
            const bool rv = (unsigned)row < (unsigned)HW;
            const float* xrow = xplane + row * HW;
            #pragma unroll
            for (int c = 0; c < 3; ++c) {
                const int col = colbase + c;
                xv[rr][c] = (rv && (unsigned)col < (unsigned)HW) ? xrow[col] : 0.f;
            }
        }
        #pragma unroll
        for (int rr = 0; rr < 3; ++rr) {
            #pragma unroll
            for (int kc = 0; kc < 3; ++kc) {
                const int k = rr * 3 + kc;
                const float4 wa = *(const float4*)(wbase + (k * 8 + l) * 16);
                const float xs0 = xv[rr][kc];       // tile 0 (row h0)
                const float xs1 = xv[rr + 1][kc];   // tile 1 (row h0+1)
                M[k][0][0] += xs0 * wa.x; M[k][1][0] += xs0 * wa.y;
                M[k][2][0] += xs0 * wa.z; M[k][3][0] += xs0 * wa.w;
                M[k][0][1] += xs1 * wa.x; M[k][1][1] += xs1 * wa.y;
                M[k][2][1] += xs1 * wa.z; M[k][3][1] += xs1 * wa.w;
            }
        }
    }

    // ---- dynamic routing (3 iters; iter 0 uniform probs = 1/9), per tile ----
    #pragma unroll
    for (int ti = 0; ti < 2; ++ti) {
        float v[4], b[9];
        {
            float s[4];
            #pragma unroll
            for (int j = 0; j < 4; ++j) {
                float a = M[0][j][ti];
                #pragma unroll
                for (int k = 1; k < 9; ++k) a += M[k][j][ti];
                s[j] = a * (1.f / 9.f);
            }
            float sq = s[0]*s[0] + s[1]*s[1] + s[2]*s[2] + s[3]*s[3];
            sq = quad_reduce(sq);
            const float scale = sq * __builtin_amdgcn_rsqf(sq) * __builtin_amdgcn_rcpf(1.f + sq);
            #pragma unroll
            for (int j = 0; j < 4; ++j) v[j] = s[j] * scale;
            #pragma unroll
            for (int k = 0; k < 9; ++k) {
                float u = M[k][0][ti]*v[0] + M[k][1][ti]*v[1]
                        + M[k][2][ti]*v[2] + M[k][3][ti]*v[3];
                b[k] = quad_reduce(u);
            }
        }

        #pragma unroll
        for (int it = 1; it < 3; ++it) {
            float mx = b[0];
            #pragma unroll
            for (int k = 1; k < 9; ++k) mx = fmaxf(mx, b[k]);
            float e[9]; float se = 0.f;
            #pragma unroll
            for (int k = 0; k < 9; ++k) { e[k] = __expf(b[k] - mx); se += e[k]; }
            const float inv = __builtin_amdgcn_rcpf(se);
            float s[4];
            #pragma unroll
            for (int j = 0; j < 4; ++j) {
                float a = 0.f;
                #pragma unroll
                for (int k = 0; k < 9; ++k) a += e[k] * M[k][j][ti];
                s[j] = a * inv;
            }
            float sq = s[0]*s[0] + s[1]*s[1] + s[2]*s[2] + s[3]*s[3];
            sq = quad_reduce(sq);
            const float scale = sq * __builtin_amdgcn_rsqf(sq) * __builtin_amdgcn_rcpf(1.f + sq);
            #pragma unroll
            for (int j = 0; j < 4; ++j) v[j] = s[j] * scale;
            if (it == 1) {
                #pragma unroll
                for (int k = 0; k < 9; ++k) {
                    float u = M[k][0][ti]*v[0] + M[k][1][ti]*v[1]
                            + M[k][2][ti]*v[2] + M[k][3][ti]*v[3];
                    b[k] += quad_reduce(u);
                }
            }
        }

        // ---- sum over p (lane bits 4,5), store row h0+ti ----
        #pragma unroll
        for (int j = 0; j < 4; ++j) {
            v[j] += __shfl_xor(v[j], 16, 64);
            v[j] += __shfl_xor(v[j], 32, 64);
        }
        if (p == 0) {
            float* op = out + ((n * 64 + o * 16 + dq * 4) * HW + (h0 + ti)) * HW + w0 + wl;
            #pragma unroll
            for (int j = 0; j < 4; ++j) op[j * HW2] = v[j];
        }
    }
}

extern "C" void kernel_launch(void* const* d_in, const int* in_sizes, int n_in,
                              void* d_out, int out_size, void* d_ws, size_t ws_size,
                              hipStream_t stream) {
    const float* x   = (const float*)d_in[0];
    const float* wgt = (const float*)d_in[1];
    float* out = (float*)d_out;

    // grid: x = n*4+o (16), y = 98 blocks of 4 wave tile-pairs
    //       392 pairs = 28 h-pairs x 14 w-tiles
    caps_routing_kernel<<<dim3(16, 98), dim3(256), 0, stream>>>(x, wgt, out);
}